// Round 12
// baseline (205.955 us; speedup 1.0000x reference)
//
#include <hip/hip_runtime.h>

// ---------- types & helpers ----------
typedef __attribute__((ext_vector_type(8))) short bf16x8;
typedef __attribute__((ext_vector_type(4))) short bf16x4;
typedef __attribute__((ext_vector_type(4))) float f32x4;

__device__ __forceinline__ float bf2f(unsigned short u) {
  unsigned int x = ((unsigned int)u) << 16;
  float f; __builtin_memcpy(&f, &x, 4); return f;
}
__device__ __forceinline__ unsigned short f2bf(float f) {
  unsigned int x; __builtin_memcpy(&x, &f, 4);
  unsigned int lsb = (x >> 16) & 1u;
  x += 0x7fffu + lsb;                 // round-to-nearest-even
  return (unsigned short)(x >> 16);
}
__device__ __forceinline__ float exp2_raw(float x) {
  float r;
  asm("v_exp_f32 %0, %1" : "=v"(r) : "v"(x));  // bare transcendental, no libm fixup
  return r;
}
// pack two f32 -> one u32 of 2 bf16 (RNE); no builtin on gfx950 (T12/m240)
__device__ __forceinline__ unsigned int cvtpk_bf16(float lo, float hi) {
  unsigned int r;
  asm("v_cvt_pk_bf16_f32 %0, %1, %2" : "=v"(r) : "v"(lo), "v"(hi));
  return r;
}
// 16x16x16 bf16 MFMA: builtin if present, else raw encoding via asm
#if __has_builtin(__builtin_amdgcn_mfma_f32_16x16x16bf16_1k)
__device__ __forceinline__ f32x4 mfma16(bf16x4 a, bf16x4 b, f32x4 c) {
  return __builtin_amdgcn_mfma_f32_16x16x16bf16_1k(a, b, c, 0, 0, 0);
}
#else
__device__ __forceinline__ f32x4 mfma16(bf16x4 a, bf16x4 b, f32x4 c) {
  f32x4 d;
  asm volatile("v_mfma_f32_16x16x16_bf16 %0, %1, %2, %3"
               : "=v"(d) : "v"(a), "v"(b), "v"(c));
  return d;
}
#endif
__device__ __forceinline__ void gload16(const unsigned short* g, unsigned short* l) {
  __builtin_amdgcn_global_load_lds(
      (const __attribute__((address_space(1))) unsigned int*)g,
      (__attribute__((address_space(3))) unsigned int*)l, 16, 0, 0);
}

// ---------- fused f32 -> bf16 convert of x, w_qkv, w_o (one launch) ----------
__global__ __launch_bounds__(256) void cvt3(const float* __restrict__ x,
                                            const float* __restrict__ wq,
                                            const float* __restrict__ wo,
                                            unsigned short* __restrict__ xb,
                                            unsigned short* __restrict__ wqb,
                                            unsigned short* __restrict__ wob) {
  const int N0 = 1048576, N1 = 786432, N2 = 524288;  // 8-elem chunks per tensor
  for (int i = blockIdx.x * 256 + threadIdx.x; i < N0 + N1 + N2;
       i += (int)(gridDim.x * 256)) {
    const float* in; unsigned short* out; int j;
    if (i < N0)            { in = x;  out = xb;  j = i; }
    else if (i < N0 + N1)  { in = wq; out = wqb; j = i - N0; }
    else                   { in = wo; out = wob; j = i - N0 - N1; }
    const float4* p = (const float4*)(in + (size_t)j * 8);
    float4 a = p[0], b = p[1];
    union { bf16x8 v; unsigned short u[8]; } o;
    o.u[0] = f2bf(a.x); o.u[1] = f2bf(a.y); o.u[2] = f2bf(a.z); o.u[3] = f2bf(a.w);
    o.u[4] = f2bf(b.x); o.u[5] = f2bf(b.y); o.u[6] = f2bf(b.z); o.u[7] = f2bf(b.w);
    *(bf16x8*)(out + (size_t)j * 8) = o.v;
  }
}

// ---------- GEMM: C[M,N] = A[M,2048] * B[N,2048]^T  (bf16 in, bf16 or f32 out) ----------
// BK=64 + XOR-swizzled staging (pre-swizzled global source, linear LDS dest,
// matching XOR on fragment read) -> ~2-way max bank aliasing.
template <int F32OUT>
__global__ __launch_bounds__(256) void gemm_bt(const unsigned short* __restrict__ A,
                                               const unsigned short* __restrict__ B,
                                               void* __restrict__ Cp, int N) {
  __shared__ unsigned short sA[128 * 64];   // 16 KB
  __shared__ unsigned short sB[128 * 64];   // 16 KB
  const int t = threadIdx.x;
  const int lane = t & 63, w = t >> 6;
  const int wm = w >> 1, wn = w & 1;
  const int l16 = lane & 15, hi = lane >> 4;
  const int m0 = blockIdx.y * 128, n0 = blockIdx.x * 128;

  f32x4 zero = {0.f, 0.f, 0.f, 0.f};
  f32x4 acc[4][4];
#pragma unroll
  for (int mi = 0; mi < 4; ++mi)
#pragma unroll
    for (int ni = 0; ni < 4; ++ni) acc[mi][ni] = zero;

  const unsigned short* gA = A + (size_t)m0 * 2048;
  const unsigned short* gB = B + (size_t)n0 * 2048;

  for (int k0 = 0; k0 < 2048; k0 += 64) {
    __syncthreads();
#pragma unroll
    for (int i = 0; i < 4; ++i) {
      int c = i * 256 + t;               // chunk 0..1023 (16B each), 8 chunks/row
      int row = c >> 3, cb = c & 7;
      gload16(gA + (size_t)row * 2048 + k0 + ((cb ^ (row & 7)) * 8), &sA[c * 8]);
    }
#pragma unroll
    for (int i = 0; i < 4; ++i) {
      int c = i * 256 + t;
      int row = c >> 3, cb = c & 7;
      gload16(gB + (size_t)row * 2048 + k0 + ((cb ^ (row & 7)) * 8), &sB[c * 8]);
    }
    __syncthreads();
#pragma unroll
    for (int kk = 0; kk < 2; ++kk) {
      bf16x8 af[4], bfr[4];
#pragma unroll
      for (int i = 0; i < 4; ++i) {
        int rowa = wm * 64 + i * 16 + l16;
        af[i]  = *(const bf16x8*)&sA[rowa * 64 + (((kk * 4 + hi) ^ (l16 & 7)) * 8)];
        int rowb = wn * 64 + i * 16 + l16;
        bfr[i] = *(const bf16x8*)&sB[rowb * 64 + (((kk * 4 + hi) ^ (l16 & 7)) * 8)];
      }
#pragma unroll
      for (int mi = 0; mi < 4; ++mi)
#pragma unroll
        for (int ni = 0; ni < 4; ++ni)
          acc[mi][ni] = __builtin_amdgcn_mfma_f32_16x16x32_bf16(af[mi], bfr[ni], acc[mi][ni], 0, 0, 0);
    }
  }

  const int rowb = m0 + wm * 64 + hi * 4;
  const int colb = n0 + wn * 64 + l16;
#pragma unroll
  for (int mi = 0; mi < 4; ++mi)
#pragma unroll
    for (int ni = 0; ni < 4; ++ni)
#pragma unroll
      for (int r = 0; r < 4; ++r) {
        size_t idx = (size_t)(rowb + mi * 16 + r) * N + colb + ni * 16;
        if (F32OUT) ((float*)Cp)[idx] = acc[mi][ni][r];
        else        ((unsigned short*)Cp)[idx] = f2bf(acc[mi][ni][r]);
      }
}

// ---------- fused prep: RoPE(q,k) scatter + V transpose (one launch) ----------
// blocks 0..639: RoPE; blocks 640..1151: V transpose.
__global__ __launch_bounds__(256) void prep(const unsigned short* __restrict__ qkv,
                                            unsigned short* __restrict__ q,
                                            unsigned short* __restrict__ k,
                                            unsigned short* __restrict__ vt) {
  __shared__ unsigned short sT[64 * 72];
  const int bid = blockIdx.x;
  if (bid < 640) {
    // ---- RoPE on q,k heads; q pre-scaled by (1/8)*log2(e) for exp2 softmax ----
    int tid = bid * 256 + threadIdx.x;  // 2*40*2048 = 163840 threads
    int l = tid & 2047;
    int rest = tid >> 11;
    int b = rest & 1;
    int h = rest >> 1;  // 0..39 (0..31 q, 32..39 k)
    const unsigned short* src = qkv + (size_t)(b * 2048 + l) * 3072 + h * 64;
    union { uint4 v[8]; unsigned short u[64]; } buf;
#pragma unroll
    for (int i = 0; i < 8; ++i) buf.v[i] = ((const uint4*)src)[i];
    const float sc = (h < 32) ? 0.125f * 1.44269504088896f : 1.0f;
#pragma unroll
    for (int j = 0; j < 32; ++j) {
      float fr = exp2f(-(float)j * 0.41524101186092033f);  // log2(10000)/32
      float ang = (float)l * fr;
      float sn, cs;
      sincosf(ang, &sn, &cs);
      float x0 = bf2f(buf.u[2 * j]), x1 = bf2f(buf.u[2 * j + 1]);
      float y0 = (x0 * cs - x1 * sn) * sc;
      float y1 = (x1 * cs + x0 * sn) * sc;
      buf.u[2 * j] = f2bf(y0);
      buf.u[2 * j + 1] = f2bf(y1);
    }
    unsigned short* dst = (h < 32) ? (q + ((size_t)(b * 32 + h) * 2048 + l) * 64)
                                   : (k + ((size_t)(b * 8 + h - 32) * 2048 + l) * 64);
#pragma unroll
    for (int i = 0; i < 8; ++i) ((uint4*)dst)[i] = buf.v[i];
  } else {
    // ---- V transpose: qkv v-heads -> VT[B,8,64,L] ----
    const int bid2 = bid - 640;        // 0..511
    const int xb = bid2 & 31, bh = bid2 >> 5;
    const int t = threadIdx.x;
    const int b = bh >> 3, h = bh & 7;
    const int l0 = xb * 64;
    const int c = t & 7, i0 = t >> 3;  // c: d-chunk, i0: 0..31
#pragma unroll
    for (int pp = 0; pp < 2; ++pp) {
      int i = i0 + pp * 32;
      const unsigned short* src =
          qkv + (size_t)(b * 2048 + l0 + i) * 3072 + 2560 + h * 64 + c * 8;
      union { bf16x8 v; unsigned short u[8]; } x;
      x.v = *(const bf16x8*)src;
#pragma unroll
      for (int e = 0; e < 8; ++e) sT[(c * 8 + e) * 72 + i] = x.u[e];
    }
    __syncthreads();
    const int d = t >> 2, ic = (t & 3) * 16;
    unsigned short* dst = vt + ((size_t)(b * 8 + h) * 64 + d) * 2048 + l0 + ic;
    *(bf16x8*)dst = *(const bf16x8*)&sT[d * 72 + ic];
    *(bf16x8*)(dst + 8) = *(const bf16x8*)&sT[d * 72 + ic + 8];
  }
}

// ---------- GQA causal flash attention (swapped QK^T, P kept in registers) ----------
// Q[B,32,L,64] (pre-scaled by 0.125*log2e), K[B,8,L,64], VT[B,8,64,L] -> Y[B,L,2048] bf16
// K/V staged once per 128-row Q-block (XOR-swizzled); block pairing (qb=pi,15-pi);
// XCD head remap. NEW: QK^T computed swapped (mfma(K,Q) -> S^T, lane holds
// [q=l16][kv=hi*4+r]) which IS the A-fragment layout of the K=16 MFMA — so
// exp + v_cvt_pk produce PV's A-operand in registers. No P LDS buffer, no
// cross-lane ops; PV and row-sums (P*ones) use 16x16x16 MFMA; O/os layouts and
// the store path are unchanged.
__global__ __launch_bounds__(256) void attn(const unsigned short* __restrict__ Q,
                                            const unsigned short* __restrict__ K,
                                            const unsigned short* __restrict__ VT,
                                            unsigned short* __restrict__ Y) {
  __shared__ unsigned short sK[128 * 64];   // 16 KB, row-major, chunk^=(row&7)
  __shared__ unsigned short sV[64 * 128];   // 16 KB, [d][col], chunk^=(d&15)
  const int t = threadIdx.x, lane = t & 63, w = t >> 6;
  const int l16 = lane & 15, hi = lane >> 4;
  const int pi = blockIdx.y;     // 0..7
  const int bx = blockIdx.x;     // 0..63
  const int head = ((bx & 7) << 3) | (bx >> 3);  // XCD-pinning permutation
  const int b = head >> 5, hq = head & 31, hkv = hq >> 2;
  const unsigned short* kp = K + (size_t)(b * 8 + hkv) * 2048 * 64;
  const unsigned short* vp = VT + (size_t)(b * 8 + hkv) * 64 * 2048;
  f32x4 zero = {0.f, 0.f, 0.f, 0.f};
  union { bf16x4 v; unsigned short u[4]; } ones_u;
#pragma unroll
  for (int j = 0; j < 4; ++j) ones_u.u[j] = 0x3F80;  // bf16 1.0
  const bf16x4 ones4 = ones_u.v;

#pragma unroll
  for (int phase = 0; phase < 2; ++phase) {
    const int qb = phase ? (15 - pi) : pi;   // q-block index, 128 rows
    const int q0 = qb * 128 + w * 32;        // this wave's 32-row tile base
    const unsigned short* qp = Q + ((size_t)(b * 32 + hq) * 2048 + q0) * 64;

    bf16x8 qf[2][2];
#pragma unroll
    for (int mi = 0; mi < 2; ++mi)
#pragma unroll
      for (int ks = 0; ks < 2; ++ks)
        qf[mi][ks] = *(const bf16x8*)(qp + (size_t)(mi * 16 + l16) * 64 + ks * 32 + hi * 8);

    f32x4 o[2][4];
    f32x4 os[2];  // row-sums via P x ones MFMA
#pragma unroll
    for (int mi = 0; mi < 2; ++mi) {
#pragma unroll
      for (int ni = 0; ni < 4; ++ni) o[mi][ni] = zero;
      os[mi] = zero;
    }

    const int nt = qb + 1;  // 128-col KV tiles (block-uniform)
    for (int tt = 0; tt < nt; ++tt) {
      const int c0 = tt * 128;
      __syncthreads();  // prior step's sK/sV reads complete before overwrite
      // --- cooperative staging, pre-swizzled global source, linear LDS dest ---
#pragma unroll
      for (int i = 0; i < 4; ++i) {
        int c = i * 256 + t;                 // K chunk 0..1023 (16B each)
        int row = c >> 3, cb = c & 7;
        gload16(kp + (size_t)(c0 + row) * 64 + ((cb ^ (row & 7)) * 8), &sK[c * 8]);
      }
#pragma unroll
      for (int i = 0; i < 4; ++i) {
        int c = i * 256 + t;                 // V chunk 0..1023
        int d = c >> 4, cb = c & 15;
        gload16(vp + (size_t)d * 2048 + c0 + ((cb ^ (d & 15)) * 8), &sV[c * 8]);
      }
      __syncthreads();  // staged tile visible (vmcnt drained by barrier)

      // --- two 64-col halves: swapped QK^T -> exp -> in-reg P -> PV ---
#pragma unroll
      for (int h = 0; h < 2; ++h) {
        const int c0h = c0 + h * 64;
        if (c0h > q0) break;  // fully-masked half for this wave (no barriers inside)
        f32x4 sc[2][4];
#pragma unroll
        for (int mi = 0; mi < 2; ++mi)
#pragma unroll
          for (int ni = 0; ni < 4; ++ni) sc[mi][ni] = zero;
#pragma unroll
        for (int ni = 0; ni < 4; ++ni) {
          const int krow = h * 64 + ni * 16 + l16;
          bf16x8 k0f = *(const bf16x8*)&sK[krow * 64 + ((hi ^ (l16 & 7)) * 8)];
          bf16x8 k1f = *(const bf16x8*)&sK[krow * 64 + (((4 + hi) ^ (l16 & 7)) * 8)];
#pragma unroll
          for (int mi = 0; mi < 2; ++mi) {  // SWAPPED: D[kv][q] -> lane [q=l16][kv=hi*4+r]
            sc[mi][ni] = __builtin_amdgcn_mfma_f32_16x16x32_bf16(k0f, qf[mi][0], sc[mi][ni], 0, 0, 0);
            sc[mi][ni] = __builtin_amdgcn_mfma_f32_16x16x32_bf16(k1f, qf[mi][1], sc[mi][ni], 0, 0, 0);
          }
        }
        if (c0h + 64 > q0) {  // boundary half: per-element causal mask (swapped mapping)
#pragma unroll
          for (int mi = 0; mi < 2; ++mi)
#pragma unroll
            for (int ni = 0; ni < 4; ++ni)
#pragma unroll
              for (int r = 0; r < 4; ++r) {
                int kv = c0h + ni * 16 + hi * 4 + r;
                int qq = q0 + mi * 16 + l16;
                if (kv > qq) sc[mi][ni][r] = -1e30f;
              }
        }
        // exp -> pack to bf16x4 (PV A-frag) -> K=16 MFMA row-sum + PV
#pragma unroll
        for (int ni = 0; ni < 4; ++ni) {
          if (c0h + ni * 16 > q0 + 16) break;  // fully-masked 16-kv block (P would be 0)
          bf16x4 pa[2];
#pragma unroll
          for (int mi = 0; mi < 2; ++mi) {
            float p0 = exp2_raw(sc[mi][ni][0]);
            float p1 = exp2_raw(sc[mi][ni][1]);
            float p2 = exp2_raw(sc[mi][ni][2]);
            float p3 = exp2_raw(sc[mi][ni][3]);
            union { unsigned int w2[2]; bf16x4 v; } pk;
            pk.w2[0] = cvtpk_bf16(p0, p1);
            pk.w2[1] = cvtpk_bf16(p2, p3);
            pa[mi] = pk.v;
            os[mi] = mfma16(pa[mi], ones4, os[mi]);
          }
          const int cb = h * 8 + ni * 2 + (hi >> 1);   // 16B chunk index of kv run
#pragma unroll
          for (int nd = 0; nd < 4; ++nd) {
            const int d = nd * 16 + l16;
            bf16x4 vb = *(const bf16x4*)&sV[d * 128 + ((cb ^ (d & 15)) * 8) + (hi & 1) * 4];
#pragma unroll
            for (int mi = 0; mi < 2; ++mi)
              o[mi][nd] = mfma16(pa[mi], vb, o[mi][nd]);
          }
        }
      }
    }
    // normalize + store (row-sum already per-lane in os[mi][r]; no reduce needed)
#pragma unroll
    for (int mi = 0; mi < 2; ++mi) {
      float inv[4];
#pragma unroll
      for (int r = 0; r < 4; ++r) inv[r] = 1.f / os[mi][r];
#pragma unroll
      for (int ni = 0; ni < 4; ++ni)
#pragma unroll
        for (int r = 0; r < 4; ++r) {
          int row = q0 + mi * 16 + hi * 4 + r;
          Y[(size_t)(b * 2048 + row) * 2048 + hq * 64 + ni * 16 + l16] =
              f2bf(o[mi][ni][r] * inv[r]);
        }
    }
  }
}

// ---------- launcher ----------
extern "C" void kernel_launch(void* const* d_in, const int* in_sizes, int n_in,
                              void* d_out, int out_size, void* d_ws, size_t ws_size,
                              hipStream_t stream) {
  const float* x    = (const float*)d_in[0];   // [2,2048,2048]
  const float* wqkv = (const float*)d_in[1];   // [3072,2048]
  const float* wo   = (const float*)d_in[2];   // [2048,2048]
  float* out = (float*)d_out;                  // [2,2048,2048] f32

  char* ws = (char*)d_ws;
  unsigned short* xb   = (unsigned short*)(ws);              // [0, 16M)  x bf16; later y
  unsigned short* wqb  = (unsigned short*)(ws + 16777216);   // dead after gemm1
  unsigned short* wob  = (unsigned short*)(ws + 29360128);
  unsigned short* qkvb = (unsigned short*)(ws + 37748736);   // dead after prep
  unsigned short* qb   = (unsigned short*)(ws + 62914560);
  unsigned short* kb   = (unsigned short*)(ws + 79691776);
  unsigned short* vtb  = (unsigned short*)(ws + 83886080);   // total 88,080,384
  unsigned short* yb = xb;  // alias: x's bf16 copy is dead after the QKV GEMM

  cvt3<<<2048, 256, 0, stream>>>(x, wqkv, wo, xb, wqb, wob);
  gemm_bt<0><<<dim3(3072 / 128, 4096 / 128), 256, 0, stream>>>(xb, wqb, qkvb, 3072);
  prep<<<1152, 256, 0, stream>>>(qkvb, qb, kb, vtb);
  attn<<<dim3(64, 8), 256, 0, stream>>>(qb, kb, vtb, yb);
  gemm_bt<1><<<dim3(2048 / 128, 4096 / 128), 256, 0, stream>>>(yb, wob, out, 2048);
}

// Round 13
// 197.883 us; speedup vs baseline: 1.0408x; 1.0408x over previous
//
#include <hip/hip_runtime.h>

// ---------- types & helpers ----------
typedef __attribute__((ext_vector_type(8))) short bf16x8;
typedef __attribute__((ext_vector_type(4))) float f32x4;

__device__ __forceinline__ float bf2f(unsigned short u) {
  unsigned int x = ((unsigned int)u) << 16;
  float f; __builtin_memcpy(&f, &x, 4); return f;
}
__device__ __forceinline__ unsigned short f2bf(float f) {
  unsigned int x; __builtin_memcpy(&x, &f, 4);
  unsigned int lsb = (x >> 16) & 1u;
  x += 0x7fffu + lsb;                 // round-to-nearest-even
  return (unsigned short)(x >> 16);
}
__device__ __forceinline__ unsigned short f2bf_trunc(float f) {
  unsigned int x; __builtin_memcpy(&x, &f, 4);
  return (unsigned short)(x >> 16);   // truncate: P>=0, bias ~2^-9 relative, fine
}
__device__ __forceinline__ float exp2_raw(float x) {
  float r;
  asm("v_exp_f32 %0, %1" : "=v"(r) : "v"(x));  // bare transcendental, no libm fixup
  return r;
}
__device__ __forceinline__ void gload16(const unsigned short* g, unsigned short* l) {
  __builtin_amdgcn_global_load_lds(
      (const __attribute__((address_space(1))) unsigned int*)g,
      (__attribute__((address_space(3))) unsigned int*)l, 16, 0, 0);
}

// ---------- fused f32 -> bf16 convert of x, w_qkv, w_o (one launch) ----------
__global__ __launch_bounds__(256) void cvt3(const float* __restrict__ x,
                                            const float* __restrict__ wq,
                                            const float* __restrict__ wo,
                                            unsigned short* __restrict__ xb,
                                            unsigned short* __restrict__ wqb,
                                            unsigned short* __restrict__ wob) {
  const int N0 = 1048576, N1 = 786432, N2 = 524288;  // 8-elem chunks per tensor
  for (int i = blockIdx.x * 256 + threadIdx.x; i < N0 + N1 + N2;
       i += (int)(gridDim.x * 256)) {
    const float* in; unsigned short* out; int j;
    if (i < N0)            { in = x;  out = xb;  j = i; }
    else if (i < N0 + N1)  { in = wq; out = wqb; j = i - N0; }
    else                   { in = wo; out = wob; j = i - N0 - N1; }
    const float4* p = (const float4*)(in + (size_t)j * 8);
    float4 a = p[0], b = p[1];
    union { bf16x8 v; unsigned short u[8]; } o;
    o.u[0] = f2bf(a.x); o.u[1] = f2bf(a.y); o.u[2] = f2bf(a.z); o.u[3] = f2bf(a.w);
    o.u[4] = f2bf(b.x); o.u[5] = f2bf(b.y); o.u[6] = f2bf(b.z); o.u[7] = f2bf(b.w);
    *(bf16x8*)(out + (size_t)j * 8) = o.v;
  }
}

// ---------- GEMM: C[M,N] = A[M,2048] * B[N,2048]^T  (bf16 in, bf16 or f32 out) ----------
// BK=64 + XOR-swizzled staging (pre-swizzled global source, linear LDS dest,
// matching XOR on fragment read) -> ~2-way max bank aliasing.
template <int F32OUT>
__global__ __launch_bounds__(256) void gemm_bt(const unsigned short* __restrict__ A,
                                               const unsigned short* __restrict__ B,
                                               void* __restrict__ Cp, int N) {
  __shared__ unsigned short sA[128 * 64];   // 16 KB
  __shared__ unsigned short sB[128 * 64];   // 16 KB
  const int t = threadIdx.x;
  const int lane = t & 63, w = t >> 6;
  const int wm = w >> 1, wn = w & 1;
  const int l16 = lane & 15, hi = lane >> 4;
  const int m0 = blockIdx.y * 128, n0 = blockIdx.x * 128;

  f32x4 zero = {0.f, 0.f, 0.f, 0.f};
  f32x4 acc[4][4];
#pragma unroll
  for (int mi = 0; mi < 4; ++mi)
#pragma unroll
    for (int ni = 0; ni < 4; ++ni) acc[mi][ni] = zero;

  const unsigned short* gA = A + (size_t)m0 * 2048;
  const unsigned short* gB = B + (size_t)n0 * 2048;

  for (int k0 = 0; k0 < 2048; k0 += 64) {
    __syncthreads();
#pragma unroll
    for (int i = 0; i < 4; ++i) {
      int c = i * 256 + t;               // chunk 0..1023 (16B each), 8 chunks/row
      int row = c >> 3, cb = c & 7;
      gload16(gA + (size_t)row * 2048 + k0 + ((cb ^ (row & 7)) * 8), &sA[c * 8]);
    }
#pragma unroll
    for (int i = 0; i < 4; ++i) {
      int c = i * 256 + t;
      int row = c >> 3, cb = c & 7;
      gload16(gB + (size_t)row * 2048 + k0 + ((cb ^ (row & 7)) * 8), &sB[c * 8]);
    }
    __syncthreads();
#pragma unroll
    for (int kk = 0; kk < 2; ++kk) {
      bf16x8 af[4], bfr[4];
#pragma unroll
      for (int i = 0; i < 4; ++i) {
        int rowa = wm * 64 + i * 16 + l16;
        af[i]  = *(const bf16x8*)&sA[rowa * 64 + (((kk * 4 + hi) ^ (l16 & 7)) * 8)];
        int rowb = wn * 64 + i * 16 + l16;
        bfr[i] = *(const bf16x8*)&sB[rowb * 64 + (((kk * 4 + hi) ^ (l16 & 7)) * 8)];
      }
#pragma unroll
      for (int mi = 0; mi < 4; ++mi)
#pragma unroll
        for (int ni = 0; ni < 4; ++ni)
          acc[mi][ni] = __builtin_amdgcn_mfma_f32_16x16x32_bf16(af[mi], bfr[ni], acc[mi][ni], 0, 0, 0);
    }
  }

  const int rowb = m0 + wm * 64 + hi * 4;
  const int colb = n0 + wn * 64 + l16;
#pragma unroll
  for (int mi = 0; mi < 4; ++mi)
#pragma unroll
    for (int ni = 0; ni < 4; ++ni)
#pragma unroll
      for (int r = 0; r < 4; ++r) {
        size_t idx = (size_t)(rowb + mi * 16 + r) * N + colb + ni * 16;
        if (F32OUT) ((float*)Cp)[idx] = acc[mi][ni][r];
        else        ((unsigned short*)Cp)[idx] = f2bf(acc[mi][ni][r]);
      }
}

// ---------- fused prep: RoPE(q,k) scatter + V transpose (one launch) ----------
// blocks 0..639: RoPE; blocks 640..1151: V transpose.
__global__ __launch_bounds__(256) void prep(const unsigned short* __restrict__ qkv,
                                            unsigned short* __restrict__ q,
                                            unsigned short* __restrict__ k,
                                            unsigned short* __restrict__ vt) {
  __shared__ unsigned short sT[64 * 72];
  const int bid = blockIdx.x;
  if (bid < 640) {
    // ---- RoPE on q,k heads; q pre-scaled by (1/8)*log2(e) for exp2 softmax ----
    int tid = bid * 256 + threadIdx.x;  // 2*40*2048 = 163840 threads
    int l = tid & 2047;
    int rest = tid >> 11;
    int b = rest & 1;
    int h = rest >> 1;  // 0..39 (0..31 q, 32..39 k)
    const unsigned short* src = qkv + (size_t)(b * 2048 + l) * 3072 + h * 64;
    union { uint4 v[8]; unsigned short u[64]; } buf;
#pragma unroll
    for (int i = 0; i < 8; ++i) buf.v[i] = ((const uint4*)src)[i];
    const float sc = (h < 32) ? 0.125f * 1.44269504088896f : 1.0f;
#pragma unroll
    for (int j = 0; j < 32; ++j) {
      float fr = exp2f(-(float)j * 0.41524101186092033f);  // log2(10000)/32
      float ang = (float)l * fr;
      float sn, cs;
      sincosf(ang, &sn, &cs);
      float x0 = bf2f(buf.u[2 * j]), x1 = bf2f(buf.u[2 * j + 1]);
      float y0 = (x0 * cs - x1 * sn) * sc;
      float y1 = (x1 * cs + x0 * sn) * sc;
      buf.u[2 * j] = f2bf(y0);
      buf.u[2 * j + 1] = f2bf(y1);
    }
    unsigned short* dst = (h < 32) ? (q + ((size_t)(b * 32 + h) * 2048 + l) * 64)
                                   : (k + ((size_t)(b * 8 + h - 32) * 2048 + l) * 64);
#pragma unroll
    for (int i = 0; i < 8; ++i) ((uint4*)dst)[i] = buf.v[i];
  } else {
    // ---- V transpose: qkv v-heads -> VT[B,8,64,L] ----
    const int bid2 = bid - 640;        // 0..511
    const int xb = bid2 & 31, bh = bid2 >> 5;
    const int t = threadIdx.x;
    const int b = bh >> 3, h = bh & 7;
    const int l0 = xb * 64;
    const int c = t & 7, i0 = t >> 3;  // c: d-chunk, i0: 0..31
#pragma unroll
    for (int pp = 0; pp < 2; ++pp) {
      int i = i0 + pp * 32;
      const unsigned short* src =
          qkv + (size_t)(b * 2048 + l0 + i) * 3072 + 2560 + h * 64 + c * 8;
      union { bf16x8 v; unsigned short u[8]; } x;
      x.v = *(const bf16x8*)src;
#pragma unroll
      for (int e = 0; e < 8; ++e) sT[(c * 8 + e) * 72 + i] = x.u[e];
    }
    __syncthreads();
    const int d = t >> 2, ic = (t & 3) * 16;
    unsigned short* dst = vt + ((size_t)(b * 8 + h) * 64 + d) * 2048 + l0 + ic;
    *(bf16x8*)dst = *(const bf16x8*)&sT[d * 72 + ic];
    *(bf16x8*)(dst + 8) = *(const bf16x8*)&sT[d * 72 + ic + 8];
  }
}

// ---------- GQA causal flash attention (128-row Q-block, LDS-shared K/V) ----------
// Q[B,32,L,64] (pre-scaled by 0.125*log2e), K[B,8,L,64], VT[B,8,64,L] -> Y[B,L,2048] bf16
// K/V staged once per 128-row Q-block (XOR-swizzled); block pairing (qb=pi,15-pi)
// for uniform 17 steps/block; XCD head remap; MFMA ones-column row-sums.
// PV runs PER 64-col HALF (right after that half's exp) so sP holds only one
// half: LDS 67.6 -> 51.2 KB => 3 blocks/CU (12 waves) instead of 2.
__global__ __launch_bounds__(256) void attn(const unsigned short* __restrict__ Q,
                                            const unsigned short* __restrict__ K,
                                            const unsigned short* __restrict__ VT,
                                            unsigned short* __restrict__ Y) {
  __shared__ unsigned short sK[128 * 64];   // 16 KB, row-major, chunk^=(row&7)
  __shared__ unsigned short sV[64 * 128];   // 16 KB, [d][col], chunk^=(d&15)
  __shared__ unsigned short sP[4][32 * 72]; // 18 KB, per-wave 32 x (64+8 pad)
  const int t = threadIdx.x, lane = t & 63, w = t >> 6;
  const int l16 = lane & 15, hi = lane >> 4;
  const int pi = blockIdx.y;     // 0..7
  const int bx = blockIdx.x;     // 0..63
  const int head = ((bx & 7) << 3) | (bx >> 3);  // XCD-pinning permutation
  const int b = head >> 5, hq = head & 31, hkv = hq >> 2;
  const unsigned short* kp = K + (size_t)(b * 8 + hkv) * 2048 * 64;
  const unsigned short* vp = VT + (size_t)(b * 8 + hkv) * 64 * 2048;
  unsigned short* sPw = sP[w];
  f32x4 zero = {0.f, 0.f, 0.f, 0.f};
  union { bf16x8 v; unsigned short u[8]; } ones_u;
#pragma unroll
  for (int j = 0; j < 8; ++j) ones_u.u[j] = 0x3F80;  // bf16 1.0
  const bf16x8 ones = ones_u.v;

#pragma unroll
  for (int phase = 0; phase < 2; ++phase) {
    const int qb = phase ? (15 - pi) : pi;   // q-block index, 128 rows
    const int q0 = qb * 128 + w * 32;        // this wave's 32-row tile base
    const unsigned short* qp = Q + ((size_t)(b * 32 + hq) * 2048 + q0) * 64;

    bf16x8 qf[2][2];
#pragma unroll
    for (int mi = 0; mi < 2; ++mi)
#pragma unroll
      for (int ks = 0; ks < 2; ++ks)
        qf[mi][ks] = *(const bf16x8*)(qp + (size_t)(mi * 16 + l16) * 64 + ks * 32 + hi * 8);

    f32x4 o[2][4];
    f32x4 os[2];  // row-sums via P x ones MFMA
#pragma unroll
    for (int mi = 0; mi < 2; ++mi) {
#pragma unroll
      for (int ni = 0; ni < 4; ++ni) o[mi][ni] = zero;
      os[mi] = zero;
    }

    const int nt = qb + 1;  // 128-col KV tiles (block-uniform)
    for (int tt = 0; tt < nt; ++tt) {
      const int c0 = tt * 128;
      __syncthreads();  // prior step's sK/sV reads complete before overwrite
      // --- cooperative staging, pre-swizzled global source, linear LDS dest ---
#pragma unroll
      for (int i = 0; i < 4; ++i) {
        int c = i * 256 + t;                 // K chunk 0..1023 (16B each)
        int row = c >> 3, cb = c & 7;
        gload16(kp + (size_t)(c0 + row) * 64 + ((cb ^ (row & 7)) * 8), &sK[c * 8]);
      }
#pragma unroll
      for (int i = 0; i < 4; ++i) {
        int c = i * 256 + t;                 // V chunk 0..1023
        int d = c >> 4, cb = c & 15;
        gload16(vp + (size_t)d * 2048 + c0 + ((cb ^ (d & 15)) * 8), &sV[c * 8]);
      }
      __syncthreads();  // staged tile visible (vmcnt drained by barrier)

      // --- two 64-col halves: QK^T + exp -> P (one half) -> PV (that half) ---
#pragma unroll
      for (int h = 0; h < 2; ++h) {
        const int c0h = c0 + h * 64;
        if (c0h > q0) break;  // fully-masked half for this wave (no barriers inside)
        f32x4 sc[2][4];
#pragma unroll
        for (int mi = 0; mi < 2; ++mi)
#pragma unroll
          for (int ni = 0; ni < 4; ++ni) sc[mi][ni] = zero;
#pragma unroll
        for (int ni = 0; ni < 4; ++ni) {
          const int krow = h * 64 + ni * 16 + l16;
          bf16x8 k0f = *(const bf16x8*)&sK[krow * 64 + ((hi ^ (l16 & 7)) * 8)];
          bf16x8 k1f = *(const bf16x8*)&sK[krow * 64 + (((4 + hi) ^ (l16 & 7)) * 8)];
#pragma unroll
          for (int mi = 0; mi < 2; ++mi) {
            sc[mi][ni] = __builtin_amdgcn_mfma_f32_16x16x32_bf16(qf[mi][0], k0f, sc[mi][ni], 0, 0, 0);
            sc[mi][ni] = __builtin_amdgcn_mfma_f32_16x16x32_bf16(qf[mi][1], k1f, sc[mi][ni], 0, 0, 0);
          }
        }
        if (c0h + 64 > q0) {  // boundary half: per-element causal mask
#pragma unroll
          for (int mi = 0; mi < 2; ++mi)
#pragma unroll
            for (int ni = 0; ni < 4; ++ni)
#pragma unroll
              for (int r = 0; r < 4; ++r) {
                int col = c0h + ni * 16 + l16;
                int row = q0 + mi * 16 + hi * 4 + r;
                if (col > row) sc[mi][ni][r] = -1e30f;
              }
        }
#pragma unroll
        for (int mi = 0; mi < 2; ++mi)
#pragma unroll
          for (int ni = 0; ni < 4; ++ni)
#pragma unroll
            for (int r = 0; r < 4; ++r) {
              float p = exp2_raw(sc[mi][ni][r]);
              sPw[(mi * 16 + hi * 4 + r) * 72 + ni * 16 + l16] = f2bf_trunc(p);
            }
        // --- PV over this half's two 32-col quarters (in-wave lgkmcnt ordering) ---
#pragma unroll
        for (int ks2 = 0; ks2 < 2; ++ks2) {
          if (c0h + ks2 * 32 > q0) break;  // wave-uniform
          bf16x8 pa[2];
#pragma unroll
          for (int mi = 0; mi < 2; ++mi) {
            pa[mi] = *(const bf16x8*)&sPw[(mi * 16 + l16) * 72 + ks2 * 32 + hi * 8];
            os[mi] = __builtin_amdgcn_mfma_f32_16x16x32_bf16(pa[mi], ones, os[mi], 0, 0, 0);
          }
#pragma unroll
          for (int ni = 0; ni < 4; ++ni) {
            const int d = ni * 16 + l16;
            bf16x8 vb = *(const bf16x8*)&sV[d * 128 + ((((h * 2 + ks2) * 4 + hi) ^ l16) * 8)];
#pragma unroll
            for (int mi = 0; mi < 2; ++mi)
              o[mi][ni] = __builtin_amdgcn_mfma_f32_16x16x32_bf16(pa[mi], vb, o[mi][ni], 0, 0, 0);
          }
        }
      }
    }
    // normalize + store (row-sum already per-lane in os[mi][r]; no reduce needed)
#pragma unroll
    for (int mi = 0; mi < 2; ++mi) {
      float inv[4];
#pragma unroll
      for (int r = 0; r < 4; ++r) inv[r] = 1.f / os[mi][r];
#pragma unroll
      for (int ni = 0; ni < 4; ++ni)
#pragma unroll
        for (int r = 0; r < 4; ++r) {
          int row = q0 + mi * 16 + hi * 4 + r;
          Y[(size_t)(b * 2048 + row) * 2048 + hq * 64 + ni * 16 + l16] =
              f2bf(o[mi][ni][r] * inv[r]);
        }
    }
  }
}

// ---------- launcher ----------
extern "C" void kernel_launch(void* const* d_in, const int* in_sizes, int n_in,
                              void* d_out, int out_size, void* d_ws, size_t ws_size,
                              hipStream_t stream) {
  const float* x    = (const float*)d_in[0];   // [2,2048,2048]
  const float* wqkv = (const float*)d_in[1];   // [3072,2048]
  const float* wo   = (const float*)d_in[2];   // [2048,2048]
  float* out = (float*)d_out;                  // [2,2048,2048] f32

  char* ws = (char*)d_ws;
  unsigned short* xb   = (unsigned short*)(ws);              // [0, 16M)  x bf16; later y
  unsigned short* wqb  = (unsigned short*)(ws + 16777216);   // dead after gemm1
  unsigned short* wob  = (unsigned short*)(ws + 29360128);
  unsigned short* qkvb = (unsigned short*)(ws + 37748736);   // dead after prep
  unsigned short* qb   = (unsigned short*)(ws + 62914560);
  unsigned short* kb   = (unsigned short*)(ws + 79691776);
  unsigned short* vtb  = (unsigned short*)(ws + 83886080);   // total 88,080,384
  unsigned short* yb = xb;  // alias: x's bf16 copy is dead after the QKV GEMM

  cvt3<<<2048, 256, 0, stream>>>(x, wqkv, wo, xb, wqb, wob);
  gemm_bt<0><<<dim3(3072 / 128, 4096 / 128), 256, 0, stream>>>(xb, wqb, qkvb, 3072);
  prep<<<1152, 256, 0, stream>>>(qkvb, qb, kb, vtb);
  attn<<<dim3(64, 8), 256, 0, stream>>>(qb, kb, vtb, yb);
  gemm_bt<1><<<dim3(2048 / 128, 4096 / 128), 256, 0, stream>>>(yb, wob, out, 2048);
}

// Round 14
// 195.718 us; speedup vs baseline: 1.0523x; 1.0111x over previous
//
#include <hip/hip_runtime.h>

// ---------- types & helpers ----------
typedef __attribute__((ext_vector_type(8))) short bf16x8;
typedef __attribute__((ext_vector_type(4))) float f32x4;

__device__ __forceinline__ float bf2f(unsigned short u) {
  unsigned int x = ((unsigned int)u) << 16;
  float f; __builtin_memcpy(&f, &x, 4); return f;
}
__device__ __forceinline__ unsigned short f2bf(float f) {
  unsigned int x; __builtin_memcpy(&x, &f, 4);
  unsigned int lsb = (x >> 16) & 1u;
  x += 0x7fffu + lsb;                 // round-to-nearest-even
  return (unsigned short)(x >> 16);
}
__device__ __forceinline__ unsigned short f2bf_trunc(float f) {
  unsigned int x; __builtin_memcpy(&x, &f, 4);
  return (unsigned short)(x >> 16);   // truncate: P>=0, bias ~2^-9 relative, fine
}
__device__ __forceinline__ float exp2_raw(float x) {
  float r;
  asm("v_exp_f32 %0, %1" : "=v"(r) : "v"(x));  // bare transcendental, no libm fixup
  return r;
}
__device__ __forceinline__ void gload16(const unsigned short* g, unsigned short* l) {
  __builtin_amdgcn_global_load_lds(
      (const __attribute__((address_space(1))) unsigned int*)g,
      (__attribute__((address_space(3))) unsigned int*)l, 16, 0, 0);
}

// ---------- fused f32 -> bf16 convert of x, w_qkv, w_o (one launch) ----------
__global__ __launch_bounds__(256) void cvt3(const float* __restrict__ x,
                                            const float* __restrict__ wq,
                                            const float* __restrict__ wo,
                                            unsigned short* __restrict__ xb,
                                            unsigned short* __restrict__ wqb,
                                            unsigned short* __restrict__ wob) {
  const int N0 = 1048576, N1 = 786432, N2 = 524288;  // 8-elem chunks per tensor
  for (int i = blockIdx.x * 256 + threadIdx.x; i < N0 + N1 + N2;
       i += (int)(gridDim.x * 256)) {
    const float* in; unsigned short* out; int j;
    if (i < N0)            { in = x;  out = xb;  j = i; }
    else if (i < N0 + N1)  { in = wq; out = wqb; j = i - N0; }
    else                   { in = wo; out = wob; j = i - N0 - N1; }
    const float4* p = (const float4*)(in + (size_t)j * 8);
    float4 a = p[0], b = p[1];
    union { bf16x8 v; unsigned short u[8]; } o;
    o.u[0] = f2bf(a.x); o.u[1] = f2bf(a.y); o.u[2] = f2bf(a.z); o.u[3] = f2bf(a.w);
    o.u[4] = f2bf(b.x); o.u[5] = f2bf(b.y); o.u[6] = f2bf(b.z); o.u[7] = f2bf(b.w);
    *(bf16x8*)(out + (size_t)j * 8) = o.v;
  }
}

// ---------- GEMM: C[M,N] = A[M,2048] * B[N,2048]^T  (bf16 in, bf16 or f32 out) ----------
// BK=64 + XOR-swizzled staging (pre-swizzled global source, linear LDS dest,
// matching XOR on fragment read) -> ~2-way max bank aliasing.
template <int F32OUT>
__global__ __launch_bounds__(256) void gemm_bt(const unsigned short* __restrict__ A,
                                               const unsigned short* __restrict__ B,
                                               void* __restrict__ Cp, int N) {
  __shared__ unsigned short sA[128 * 64];   // 16 KB
  __shared__ unsigned short sB[128 * 64];   // 16 KB
  const int t = threadIdx.x;
  const int lane = t & 63, w = t >> 6;
  const int wm = w >> 1, wn = w & 1;
  const int l16 = lane & 15, hi = lane >> 4;
  const int m0 = blockIdx.y * 128, n0 = blockIdx.x * 128;

  f32x4 zero = {0.f, 0.f, 0.f, 0.f};
  f32x4 acc[4][4];
#pragma unroll
  for (int mi = 0; mi < 4; ++mi)
#pragma unroll
    for (int ni = 0; ni < 4; ++ni) acc[mi][ni] = zero;

  const unsigned short* gA = A + (size_t)m0 * 2048;
  const unsigned short* gB = B + (size_t)n0 * 2048;

  for (int k0 = 0; k0 < 2048; k0 += 64) {
    __syncthreads();
#pragma unroll
    for (int i = 0; i < 4; ++i) {
      int c = i * 256 + t;               // chunk 0..1023 (16B each), 8 chunks/row
      int row = c >> 3, cb = c & 7;
      gload16(gA + (size_t)row * 2048 + k0 + ((cb ^ (row & 7)) * 8), &sA[c * 8]);
    }
#pragma unroll
    for (int i = 0; i < 4; ++i) {
      int c = i * 256 + t;
      int row = c >> 3, cb = c & 7;
      gload16(gB + (size_t)row * 2048 + k0 + ((cb ^ (row & 7)) * 8), &sB[c * 8]);
    }
    __syncthreads();
#pragma unroll
    for (int kk = 0; kk < 2; ++kk) {
      bf16x8 af[4], bfr[4];
#pragma unroll
      for (int i = 0; i < 4; ++i) {
        int rowa = wm * 64 + i * 16 + l16;
        af[i]  = *(const bf16x8*)&sA[rowa * 64 + (((kk * 4 + hi) ^ (l16 & 7)) * 8)];
        int rowb = wn * 64 + i * 16 + l16;
        bfr[i] = *(const bf16x8*)&sB[rowb * 64 + (((kk * 4 + hi) ^ (l16 & 7)) * 8)];
      }
#pragma unroll
      for (int mi = 0; mi < 4; ++mi)
#pragma unroll
        for (int ni = 0; ni < 4; ++ni)
          acc[mi][ni] = __builtin_amdgcn_mfma_f32_16x16x32_bf16(af[mi], bfr[ni], acc[mi][ni], 0, 0, 0);
    }
  }

  const int rowb = m0 + wm * 64 + hi * 4;
  const int colb = n0 + wn * 64 + l16;
#pragma unroll
  for (int mi = 0; mi < 4; ++mi)
#pragma unroll
    for (int ni = 0; ni < 4; ++ni)
#pragma unroll
      for (int r = 0; r < 4; ++r) {
        size_t idx = (size_t)(rowb + mi * 16 + r) * N + colb + ni * 16;
        if (F32OUT) ((float*)Cp)[idx] = acc[mi][ni][r];
        else        ((unsigned short*)Cp)[idx] = f2bf(acc[mi][ni][r]);
      }
}

// ---------- fused prep: RoPE(q,k) scatter + V transpose (one launch) ----------
// blocks 0..639: RoPE; blocks 640..1151: V transpose.
__global__ __launch_bounds__(256) void prep(const unsigned short* __restrict__ qkv,
                                            unsigned short* __restrict__ q,
                                            unsigned short* __restrict__ k,
                                            unsigned short* __restrict__ vt) {
  __shared__ unsigned short sT[64 * 72];
  const int bid = blockIdx.x;
  if (bid < 640) {
    // ---- RoPE on q,k heads; q pre-scaled by (1/8)*log2(e) for exp2 softmax ----
    int tid = bid * 256 + threadIdx.x;  // 2*40*2048 = 163840 threads
    int l = tid & 2047;
    int rest = tid >> 11;
    int b = rest & 1;
    int h = rest >> 1;  // 0..39 (0..31 q, 32..39 k)
    const unsigned short* src = qkv + (size_t)(b * 2048 + l) * 3072 + h * 64;
    union { uint4 v[8]; unsigned short u[64]; } buf;
#pragma unroll
    for (int i = 0; i < 8; ++i) buf.v[i] = ((const uint4*)src)[i];
    const float sc = (h < 32) ? 0.125f * 1.44269504088896f : 1.0f;
#pragma unroll
    for (int j = 0; j < 32; ++j) {
      float fr = exp2f(-(float)j * 0.41524101186092033f);  // log2(10000)/32
      float ang = (float)l * fr;
      float sn, cs;
      sincosf(ang, &sn, &cs);
      float x0 = bf2f(buf.u[2 * j]), x1 = bf2f(buf.u[2 * j + 1]);
      float y0 = (x0 * cs - x1 * sn) * sc;
      float y1 = (x1 * cs + x0 * sn) * sc;
      buf.u[2 * j] = f2bf(y0);
      buf.u[2 * j + 1] = f2bf(y1);
    }
    unsigned short* dst = (h < 32) ? (q + ((size_t)(b * 32 + h) * 2048 + l) * 64)
                                   : (k + ((size_t)(b * 8 + h - 32) * 2048 + l) * 64);
#pragma unroll
    for (int i = 0; i < 8; ++i) ((uint4*)dst)[i] = buf.v[i];
  } else {
    // ---- V transpose: qkv v-heads -> VT[B,8,64,L] ----
    const int bid2 = bid - 640;        // 0..511
    const int xb = bid2 & 31, bh = bid2 >> 5;
    const int t = threadIdx.x;
    const int b = bh >> 3, h = bh & 7;
    const int l0 = xb * 64;
    const int c = t & 7, i0 = t >> 3;  // c: d-chunk, i0: 0..31
#pragma unroll
    for (int pp = 0; pp < 2; ++pp) {
      int i = i0 + pp * 32;
      const unsigned short* src =
          qkv + (size_t)(b * 2048 + l0 + i) * 3072 + 2560 + h * 64 + c * 8;
      union { bf16x8 v; unsigned short u[8]; } x;
      x.v = *(const bf16x8*)src;
#pragma unroll
      for (int e = 0; e < 8; ++e) sT[(c * 8 + e) * 72 + i] = x.u[e];
    }
    __syncthreads();
    const int d = t >> 2, ic = (t & 3) * 16;
    unsigned short* dst = vt + ((size_t)(b * 8 + h) * 64 + d) * 2048 + l0 + ic;
    *(bf16x8*)dst = *(const bf16x8*)&sT[d * 72 + ic];
    *(bf16x8*)(dst + 8) = *(const bf16x8*)&sT[d * 72 + ic + 8];
  }
}

// ---------- GQA causal flash attention (128-row Q-block, LDS-shared K/V) ----------
// Q[B,32,L,64] (pre-scaled by 0.125*log2e), K[B,8,L,64], VT[B,8,64,L] -> Y[B,L,2048] bf16
// One block per (head, 128-row q-block): grid 64x16 = 1024 blocks -> 3 resident
// blocks/CU (LDS-capped) + 256 backfill for LPT balance. Heavy q-blocks first
// (x is the fast grid dim). K/V staged once per block (XOR-swizzled); XCD head
// remap (block id ≡ bx mod 8); MFMA ones-column row-sums; per-half PV.
__global__ __launch_bounds__(256) void attn(const unsigned short* __restrict__ Q,
                                            const unsigned short* __restrict__ K,
                                            const unsigned short* __restrict__ VT,
                                            unsigned short* __restrict__ Y) {
  __shared__ unsigned short sK[128 * 64];   // 16 KB, row-major, chunk^=(row&7)
  __shared__ unsigned short sV[64 * 128];   // 16 KB, [d][col], chunk^=(d&15)
  __shared__ unsigned short sP[4][32 * 72]; // 18 KB, per-wave 32 x (64+8 pad)
  const int t = threadIdx.x, lane = t & 63, w = t >> 6;
  const int l16 = lane & 15, hi = lane >> 4;
  const int qb = 15 - (int)blockIdx.y;           // q-block 15..0, heavy first
  const int bx = blockIdx.x;                     // 0..63
  const int head = ((bx & 7) << 3) | (bx >> 3);  // XCD-pinning permutation
  const int b = head >> 5, hq = head & 31, hkv = hq >> 2;
  const unsigned short* kp = K + (size_t)(b * 8 + hkv) * 2048 * 64;
  const unsigned short* vp = VT + (size_t)(b * 8 + hkv) * 64 * 2048;
  unsigned short* sPw = sP[w];
  f32x4 zero = {0.f, 0.f, 0.f, 0.f};
  union { bf16x8 v; unsigned short u[8]; } ones_u;
#pragma unroll
  for (int j = 0; j < 8; ++j) ones_u.u[j] = 0x3F80;  // bf16 1.0
  const bf16x8 ones = ones_u.v;

  const int q0 = qb * 128 + w * 32;        // this wave's 32-row tile base
  const unsigned short* qp = Q + ((size_t)(b * 32 + hq) * 2048 + q0) * 64;

  bf16x8 qf[2][2];
#pragma unroll
  for (int mi = 0; mi < 2; ++mi)
#pragma unroll
    for (int ks = 0; ks < 2; ++ks)
      qf[mi][ks] = *(const bf16x8*)(qp + (size_t)(mi * 16 + l16) * 64 + ks * 32 + hi * 8);

  f32x4 o[2][4];
  f32x4 os[2];  // row-sums via P x ones MFMA
#pragma unroll
  for (int mi = 0; mi < 2; ++mi) {
#pragma unroll
    for (int ni = 0; ni < 4; ++ni) o[mi][ni] = zero;
    os[mi] = zero;
  }

  const int nt = qb + 1;  // 128-col KV tiles (block-uniform)
  for (int tt = 0; tt < nt; ++tt) {
    const int c0 = tt * 128;
    __syncthreads();  // prior step's sK/sV reads complete before overwrite
    // --- cooperative staging, pre-swizzled global source, linear LDS dest ---
#pragma unroll
    for (int i = 0; i < 4; ++i) {
      int c = i * 256 + t;                 // K chunk 0..1023 (16B each)
      int row = c >> 3, cb = c & 7;
      gload16(kp + (size_t)(c0 + row) * 64 + ((cb ^ (row & 7)) * 8), &sK[c * 8]);
    }
#pragma unroll
    for (int i = 0; i < 4; ++i) {
      int c = i * 256 + t;                 // V chunk 0..1023
      int d = c >> 4, cb = c & 15;
      gload16(vp + (size_t)d * 2048 + c0 + ((cb ^ (d & 15)) * 8), &sV[c * 8]);
    }
    __syncthreads();  // staged tile visible (vmcnt drained by barrier)

    // --- two 64-col halves: QK^T + exp -> P (one half) -> PV (that half) ---
#pragma unroll
    for (int h = 0; h < 2; ++h) {
      const int c0h = c0 + h * 64;
      if (c0h > q0) break;  // fully-masked half for this wave (no barriers inside)
      f32x4 sc[2][4];
#pragma unroll
      for (int mi = 0; mi < 2; ++mi)
#pragma unroll
        for (int ni = 0; ni < 4; ++ni) sc[mi][ni] = zero;
#pragma unroll
      for (int ni = 0; ni < 4; ++ni) {
        const int krow = h * 64 + ni * 16 + l16;
        bf16x8 k0f = *(const bf16x8*)&sK[krow * 64 + ((hi ^ (l16 & 7)) * 8)];
        bf16x8 k1f = *(const bf16x8*)&sK[krow * 64 + (((4 + hi) ^ (l16 & 7)) * 8)];
#pragma unroll
        for (int mi = 0; mi < 2; ++mi) {
          sc[mi][ni] = __builtin_amdgcn_mfma_f32_16x16x32_bf16(qf[mi][0], k0f, sc[mi][ni], 0, 0, 0);
          sc[mi][ni] = __builtin_amdgcn_mfma_f32_16x16x32_bf16(qf[mi][1], k1f, sc[mi][ni], 0, 0, 0);
        }
      }
      if (c0h + 64 > q0) {  // boundary half: per-element causal mask
#pragma unroll
        for (int mi = 0; mi < 2; ++mi)
#pragma unroll
          for (int ni = 0; ni < 4; ++ni)
#pragma unroll
            for (int r = 0; r < 4; ++r) {
              int col = c0h + ni * 16 + l16;
              int row = q0 + mi * 16 + hi * 4 + r;
              if (col > row) sc[mi][ni][r] = -1e30f;
            }
      }
#pragma unroll
      for (int mi = 0; mi < 2; ++mi)
#pragma unroll
        for (int ni = 0; ni < 4; ++ni)
#pragma unroll
          for (int r = 0; r < 4; ++r) {
            float p = exp2_raw(sc[mi][ni][r]);
            sPw[(mi * 16 + hi * 4 + r) * 72 + ni * 16 + l16] = f2bf_trunc(p);
          }
      // --- PV over this half's two 32-col quarters (in-wave lgkmcnt ordering) ---
#pragma unroll
      for (int ks2 = 0; ks2 < 2; ++ks2) {
        if (c0h + ks2 * 32 > q0) break;  // wave-uniform
        bf16x8 pa[2];
#pragma unroll
        for (int mi = 0; mi < 2; ++mi) {
          pa[mi] = *(const bf16x8*)&sPw[(mi * 16 + l16) * 72 + ks2 * 32 + hi * 8];
          os[mi] = __builtin_amdgcn_mfma_f32_16x16x32_bf16(pa[mi], ones, os[mi], 0, 0, 0);
        }
#pragma unroll
        for (int ni = 0; ni < 4; ++ni) {
          const int d = ni * 16 + l16;
          bf16x8 vb = *(const bf16x8*)&sV[d * 128 + ((((h * 2 + ks2) * 4 + hi) ^ l16) * 8)];
#pragma unroll
          for (int mi = 0; mi < 2; ++mi)
            o[mi][ni] = __builtin_amdgcn_mfma_f32_16x16x32_bf16(pa[mi], vb, o[mi][ni], 0, 0, 0);
        }
      }
    }
  }
  // normalize + store (row-sum already per-lane in os[mi][r]; no reduce needed)
#pragma unroll
  for (int mi = 0; mi < 2; ++mi) {
    float inv[4];
#pragma unroll
    for (int r = 0; r < 4; ++r) inv[r] = 1.f / os[mi][r];
#pragma unroll
    for (int ni = 0; ni < 4; ++ni)
#pragma unroll
      for (int r = 0; r < 4; ++r) {
        int row = q0 + mi * 16 + hi * 4 + r;
        Y[(size_t)(b * 2048 + row) * 2048 + hq * 64 + ni * 16 + l16] =
            f2bf(o[mi][ni][r] * inv[r]);
      }
  }
}

// ---------- launcher ----------
extern "C" void kernel_launch(void* const* d_in, const int* in_sizes, int n_in,
                              void* d_out, int out_size, void* d_ws, size_t ws_size,
                              hipStream_t stream) {
  const float* x    = (const float*)d_in[0];   // [2,2048,2048]
  const float* wqkv = (const float*)d_in[1];   // [3072,2048]
  const float* wo   = (const float*)d_in[2];   // [2048,2048]
  float* out = (float*)d_out;                  // [2,2048,2048] f32

  char* ws = (char*)d_ws;
  unsigned short* xb   = (unsigned short*)(ws);              // [0, 16M)  x bf16; later y
  unsigned short* wqb  = (unsigned short*)(ws + 16777216);   // dead after gemm1
  unsigned short* wob  = (unsigned short*)(ws + 29360128);
  unsigned short* qkvb = (unsigned short*)(ws + 37748736);   // dead after prep
  unsigned short* qb   = (unsigned short*)(ws + 62914560);
  unsigned short* kb   = (unsigned short*)(ws + 79691776);
  unsigned short* vtb  = (unsigned short*)(ws + 83886080);   // total 88,080,384
  unsigned short* yb = xb;  // alias: x's bf16 copy is dead after the QKV GEMM

  cvt3<<<2048, 256, 0, stream>>>(x, wqkv, wo, xb, wqb, wob);
  gemm_bt<0><<<dim3(3072 / 128, 4096 / 128), 256, 0, stream>>>(xb, wqb, qkvb, 3072);
  prep<<<1152, 256, 0, stream>>>(qkvb, qb, kb, vtb);
  attn<<<dim3(64, 16), 256, 0, stream>>>(qb, kb, vtb, yb);
  gemm_bt<1><<<dim3(2048 / 128, 4096 / 128), 256, 0, stream>>>(yb, wob, out, 2048);
}